// Round 2
// baseline (619.432 us; speedup 1.0000x reference)
//
#include <hip/hip_runtime.h>
#include <stdint.h>

#define C_IN 512
#define HW 4096
#define NPIX 65536
#define KPAD 544
#define KIN 537
#define HID 512

typedef __attribute__((ext_vector_type(8))) short bf16x8;
typedef __attribute__((ext_vector_type(4))) short bf16x4_t;
typedef __attribute__((ext_vector_type(4))) float f32x4;

__device__ __forceinline__ unsigned short f2bf(float f) {
  union { float f; uint32_t u; } v; v.f = f;
  uint32_t u = v.u;
  return (unsigned short)((u + 0x7fffu + ((u >> 16) & 1u)) >> 16);
}
__device__ __forceinline__ float bf2f(unsigned short h) {
  union { uint32_t u; float f; } v; v.u = ((uint32_t)h) << 16;
  return v.f;
}

// ---------- W: fp32 (512x537) -> bf16 (512x544, zero-padded cols) ----------
__global__ void k_wconv(const float* __restrict__ W, unsigned short* __restrict__ Wb) {
  int idx = blockIdx.x * 256 + threadIdx.x;
  if (idx >= HID * KPAD) return;
  int o = idx / KPAD;
  int k = idx - o * KPAD;
  float v = (k < KIN) ? W[o * KIN + k] : 0.f;
  Wb[idx] = f2bf(v);
}

// ---------- correlation partials (8-way channel split) + x -> featB[n][c] ----------
// grid 512: bid = (cs | tile | b); block 256 = (tr 0..7, tc 0..31); 4 pixels/thread
#define PADT 36
#define SMN (4 * PADT * PADT)

__global__ __launch_bounds__(256) void k_corr(const float* __restrict__ x,
                                              unsigned short* __restrict__ featB,
                                              unsigned short* __restrict__ part) {
  int bid = blockIdx.x;
  int cs = bid & 7;
  int t = bid >> 3;
  int bb = t >> 2;
  int tile = t & 3;
  int h0 = (tile >> 1) * 32, w0 = (tile & 1) * 32;
  int tid = threadIdx.x;
  int tr = tid >> 5;
  int tc = tid & 31;
  __shared__ float sm[SMN];

  float acc[4][25];
#pragma unroll
  for (int p = 0; p < 4; ++p)
#pragma unroll
    for (int k = 0; k < 25; ++k) acc[p][k] = 0.f;

  const float* xb = x + (size_t)bb * C_IN * HW;
  int nbase = bb * HW + (h0 + tr * 4) * 64 + (w0 + tc);

  for (int st = 0; st < 16; ++st) {
    int c0 = cs * 64 + st * 4;
    __syncthreads();
    for (int li = tid; li < SMN; li += 256) {
      int ci = li / (PADT * PADT);
      int rem = li - ci * (PADT * PADT);
      int r = rem / PADT;
      int cl = rem - r * PADT;
      int gh = h0 + r - 2, gw = w0 + cl - 2;
      float v = 0.f;
      if ((unsigned)gh < 64u && (unsigned)gw < 64u)
        v = xb[(size_t)(c0 + ci) * HW + gh * 64 + gw];
      sm[li] = v;
    }
    __syncthreads();
    unsigned short xs[4][4];
#pragma unroll
    for (int ci = 0; ci < 4; ++ci) {
      const float* s = &sm[ci * PADT * PADT];
      float v[8][5];
#pragma unroll
      for (int rr = 0; rr < 8; ++rr)
#pragma unroll
        for (int cc = 0; cc < 5; ++cc)
          v[rr][cc] = s[(tr * 4 + rr) * PADT + (tc + cc)];
#pragma unroll
      for (int p = 0; p < 4; ++p) {
        float xc = v[p + 2][2];
        xs[p][ci] = f2bf(xc);
#pragma unroll
        for (int di = 0; di < 5; ++di)
#pragma unroll
          for (int dj = 0; dj < 5; ++dj)
            acc[p][di * 5 + dj] += xc * v[p + di][dj];
      }
    }
#pragma unroll
    for (int p = 0; p < 4; ++p) {
      int n = nbase + p * 64;
      *(bf16x4_t*)(featB + (size_t)n * KPAD + c0) = *(bf16x4_t*)&xs[p][0];
    }
  }
#pragma unroll
  for (int p = 0; p < 4; ++p) {
    int n = nbase + p * 64;
#pragma unroll
    for (int k = 0; k < 25; ++k)
      part[((size_t)cs * 25 + k) * NPIX + n] = f2bf(acc[p][k]);
  }
}

// ---------- reduce partials, L2-normalize, emit featB[n][512..543] ----------
__global__ void k_norm(const unsigned short* __restrict__ part,
                       unsigned short* __restrict__ featB) {
  int n = blockIdx.x * 256 + threadIdx.x;
  float g[25];
  float ss = 0.f;
#pragma unroll
  for (int k = 0; k < 25; ++k) {
    float s = 0.f;
#pragma unroll
    for (int cs = 0; cs < 8; ++cs)
      s += bf2f(part[((size_t)cs * 25 + k) * NPIX + n]);
    g[k] = s;
    ss += s * s;
  }
  float inv = 1.0f / sqrtf(ss + 1e-6f);
  unsigned short buf[32];
#pragma unroll
  for (int k = 0; k < 25; ++k) buf[k] = f2bf(g[k] * inv);
#pragma unroll
  for (int k = 25; k < 32; ++k) buf[k] = 0;
#pragma unroll
  for (int j = 0; j < 4; ++j)
    *(bf16x8*)(featB + (size_t)n * KPAD + 512 + j * 8) = *(bf16x8*)&buf[j * 8];
}

// ---------- GEMM: out(512 x 65536) = Wb(512 x 544) * featB(65536 x 544)^T ----------
typedef __attribute__((address_space(3))) unsigned int as3_uint;
typedef const __attribute__((address_space(1))) unsigned int as1_uint;

__device__ __forceinline__ void glds16(const void* g, void* l) {
  __builtin_amdgcn_global_load_lds((as1_uint*)g, (as3_uint*)l, 16, 0, 0);
}

__global__ __launch_bounds__(256) void k_gemm(const unsigned short* __restrict__ Wb,
                                              const unsigned short* __restrict__ featB,
                                              const float* __restrict__ bias,
                                              float* __restrict__ out) {
  __shared__ __attribute__((aligned(16))) unsigned short As[2][4096]; // [128 m][32 k], swz
  __shared__ __attribute__((aligned(16))) unsigned short Bs[2][4096]; // [128 n][32 k], swz
  // XCD-aware bijective swizzle (2048 = 8*256): 4 M-tiles of one N-tile -> same XCD
  int g = blockIdx.x;
  int bid = (g & 7) * 256 + (g >> 3);
  int mt = bid & 3;
  int nt = bid >> 2;
  int m0 = mt * 128;
  int n0 = nt * 128;
  int tid = threadIdx.x;
  int wave = tid >> 6;
  int lane = tid & 63;
  int wm = wave >> 1;
  int wn = wave & 1;
  int kg = lane >> 4;

  // fragment read offsets (byte), XOR-swizzled to match staged layout
  uint32_t aOff[4], bOff[4];
#pragma unroll
  for (int r = 0; r < 4; ++r) {
    int rr = wm * 64 + r * 16 + (lane & 15);
    aOff[r] = rr * 64 + ((kg ^ ((rr >> 1) & 3)) << 4);
  }
#pragma unroll
  for (int cb = 0; cb < 4; ++cb) {
    int rr = wn * 64 + cb * 16 + (lane & 15);
    bOff[cb] = rr * 64 + ((kg ^ ((rr >> 1) & 3)) << 4);
  }

  f32x4 acc[4][4];
#pragma unroll
  for (int r = 0; r < 4; ++r)
#pragma unroll
    for (int cb = 0; cb < 4; ++cb)
      acc[r][cb] = (f32x4){0.f, 0.f, 0.f, 0.f};

  // stage one [128][32] tile pair; linear LDS dest (uniform base + lane*16),
  // pre-swizzled global source (rule #21)
  auto STAGE = [&](int buf, int k0) {
#pragma unroll
    for (int q = 0; q < 2; ++q) {
      int c = wave * 2 + q;
      int i = c * 64 + lane;
      int r = i >> 2;
      int slot = i & 3;
      int k8 = slot ^ ((r >> 1) & 3);
      glds16(Wb + (size_t)(m0 + r) * KPAD + k0 + k8 * 8, (char*)&As[buf][0] + c * 1024);
      glds16(featB + (size_t)(n0 + r) * KPAD + k0 + k8 * 8, (char*)&Bs[buf][0] + c * 1024);
    }
  };

  STAGE(0, 0);
  __syncthreads();
  int cur = 0;
#pragma unroll 1
  for (int t = 0; t < 17; ++t) {
    if (t < 16) STAGE(cur ^ 1, (t + 1) * 32);
    const char* Ab = (const char*)&As[cur][0];
    const char* Bb = (const char*)&Bs[cur][0];
    bf16x8 af[4], bf[4];
#pragma unroll
    for (int r = 0; r < 4; ++r)
      af[r] = *(const bf16x8*)(Ab + aOff[r]);
#pragma unroll
    for (int cb = 0; cb < 4; ++cb)
      bf[cb] = *(const bf16x8*)(Bb + bOff[cb]);
#pragma unroll
    for (int cb = 0; cb < 4; ++cb)
#pragma unroll
      for (int r = 0; r < 4; ++r)
        acc[r][cb] = __builtin_amdgcn_mfma_f32_16x16x32_bf16(af[r], bf[cb], acc[r][cb], 0, 0, 0);
    __syncthreads();
    cur ^= 1;
  }

  int bb = n0 >> 12;
  int hwb = n0 & 4095;
  float* outb = out + (size_t)bb * (HID * HW) + hwb;
#pragma unroll
  for (int r = 0; r < 4; ++r) {
    int row0 = m0 + wm * 64 + r * 16 + (lane >> 4) * 4;
    float bv[4];
#pragma unroll
    for (int j = 0; j < 4; ++j) bv[j] = bias[row0 + j];
#pragma unroll
    for (int cb = 0; cb < 4; ++cb) {
      int col = wn * 64 + cb * 16 + (lane & 15);
#pragma unroll
      for (int j = 0; j < 4; ++j) {
        float v2 = acc[r][cb][j] + bv[j];
        v2 = fmaxf(v2, 0.f);
        outb[(size_t)(row0 + j) * HW + col] = v2;
      }
    }
  }
}

extern "C" void kernel_launch(void* const* d_in, const int* in_sizes, int n_in,
                              void* d_out, int out_size, void* d_ws, size_t ws_size,
                              hipStream_t stream) {
  const float* x = (const float*)d_in[0];
  const float* W = (const float*)d_in[1];
  const float* bias = (const float*)d_in[2];
  float* out = (float*)d_out;
  char* ws = (char*)d_ws;
  // ws layout: featB (65536 x 544 bf16) = 71,303,168 B
  //            Wb    (512 x 544  bf16)  =    557,056 B
  //            part  (8 x 25 x 65536 bf16) = 26,214,400 B   (total ~98.1 MB)
  unsigned short* featB = (unsigned short*)ws;
  unsigned short* Wb = (unsigned short*)(ws + 71303168);
  unsigned short* part = (unsigned short*)(ws + 71860224);

  k_wconv<<<1088, 256, 0, stream>>>(W, Wb);
  k_corr<<<512, 256, 0, stream>>>(x, featB, part);
  k_norm<<<256, 256, 0, stream>>>(part, featB);
  k_gemm<<<2048, 256, 0, stream>>>(Wb, featB, bias, out);
}